// Round 3
// baseline (173.146 us; speedup 1.0000x reference)
//
#include <hip/hip_runtime.h>
#include <hip/hip_bf16.h>

#define N 4096
#define D 128
#define TJ 128        // j-tile (X rows, C rows)
#define TI 64         // i-tile (Y rows, C cols)
#define LDP 72        // 64 K-chunk + 8 bf16 pad

typedef __attribute__((ext_vector_type(8))) short short8;
typedef __attribute__((ext_vector_type(4))) float f32x4;

#define LOG2E 1.44269504088896340736f
#define LN2   0.69314718055994530942f

#if __has_builtin(__builtin_amdgcn_rcpf)
__device__ __forceinline__ float fast_rcp(float x) { return __builtin_amdgcn_rcpf(x); }
#else
__device__ __forceinline__ float fast_rcp(float x) { return 1.f / x; }
#endif
#if __has_builtin(__builtin_amdgcn_logf)
__device__ __forceinline__ float fast_log2(float x) { return __builtin_amdgcn_logf(x); }
#else
__device__ __forceinline__ float fast_log2(float x) { return __log2f(x); }
#endif
#if __has_builtin(__builtin_amdgcn_exp2f)
__device__ __forceinline__ float fast_exp2(float x) { return __builtin_amdgcn_exp2f(x); }
#else
__device__ __forceinline__ float fast_exp2(float x) { return exp2f(x); }
#endif

__device__ __forceinline__ float sig_nl2(float nl2) {  // sigmoid(x), nl2 = -x*log2e
    return fast_rcp(1.f + fast_exp2(nl2));
}

// ---------------- kernel 0: cast to bf16, exact fp32 row norms, zero accumulators ----------------
__global__ __launch_bounds__(128) void k_prep(
    const float* __restrict__ X, const float* __restrict__ Y,
    __hip_bfloat16* __restrict__ Xb, __hip_bfloat16* __restrict__ Yb,
    float* __restrict__ xn, float* __restrict__ yn,
    float* __restrict__ R, float* __restrict__ TLr, float* __restrict__ sc)
{
    const int row = blockIdx.x, t = threadIdx.x;
    const float vx = X[row * D + t], vy = Y[row * D + t];
    Xb[row * D + t] = __float2bfloat16(vx);
    Yb[row * D + t] = __float2bfloat16(vy);
    float px = vx * vx, py = vy * vy;
#pragma unroll
    for (int m = 1; m < 64; m <<= 1) { px += __shfl_xor(px, m); py += __shfl_xor(py, m); }
    __shared__ float s[2][2];
    if ((t & 63) == 0) { s[t >> 6][0] = px; s[t >> 6][1] = py; }
    __syncthreads();
    if (t == 0) { xn[row] = s[0][0] + s[1][0]; yn[row] = s[0][1] + s[1][1]; }
    const int g = row * D + t;
    if (g < N) { R[g] = 0.f; TLr[g] = 0.f; }
    if (g < 16) sc[g] = 0.f;
}

// ---------------- matmul + fused epilogue, 128(j) x 64(i) tile, 4 waves of 32j x 64i ----------------
// C layout (transposed problem): C rows = j (X), C cols = i (Y).
// PASS=1: per-i sums of log2(1+s2) and 1/(1+s2); PASS=2: global sums (way-log2, 2 sigmoids)
template <int PASS>
__global__ __launch_bounds__(256) void k_mat(
    const __hip_bfloat16* __restrict__ Yb, const __hip_bfloat16* __restrict__ Xb,
    const float* __restrict__ yn, const float* __restrict__ xn,
    float* __restrict__ pos, float* __restrict__ R, float* __restrict__ TLr,
    float* __restrict__ sc)
{
    __shared__ short ldsX[TJ * LDP];          // j side (A operand)
    __shared__ short ldsY[TI * LDP];          // i side (B operand)
    __shared__ __align__(16) float ldsXn[TJ];
    __shared__ __align__(16) float ldsYn[TI];
    __shared__ float rowA[TI], rowB[TI];      // PASS1: log2L / E per-i acc; PASS2: rowB = exp(pos_i)
    __shared__ float wred[4][3];

    const int tid = threadIdx.x;
    const int bm = blockIdx.y, bn = blockIdx.x;
    const int j0 = bm * TJ, i0 = bn * TI;
    const int lane = tid & 63, wave = tid >> 6;
    const int wj = wave * 32;                 // this wave's j strip
    const int l16 = lane & 15, quad = lane >> 4;

    if (tid < TJ) ldsXn[tid] = xn[j0 + tid];
    if (tid < TI) {
        ldsYn[tid] = yn[i0 + tid];
        if (PASS == 1) { rowA[tid] = 0.f; rowB[tid] = 0.f; }
        else rowB[tid] = fast_exp2(pos[i0 + tid] * LOG2E);
    }
    const float LB = (PASS == 2) ? sc[3] : 0.f;
    const float C2 = (PASS == 2) ? 2.f * fast_exp2(LB * LOG2E) : 0.f;

    f32x4 acc[2][4];
#pragma unroll
    for (int a = 0; a < 2; a++)
#pragma unroll
        for (int b = 0; b < 4; b++) acc[a][b] = f32x4{0.f, 0.f, 0.f, 0.f};

#pragma unroll
    for (int ks = 0; ks < 2; ++ks) {
        if (ks) __syncthreads();
        const int4* gx = (const int4*)(Xb + (size_t)j0 * D + ks * 64);
        const int4* gy = (const int4*)(Yb + (size_t)i0 * D + ks * 64);
#pragma unroll
        for (int u = 0; u < 4; u++) {
            int e = tid + u * 256;
            int r = e >> 3, c = e & 7;
            *(int4*)&ldsX[r * LDP + c * 8] = gx[r * 16 + c];
        }
#pragma unroll
        for (int u = 0; u < 2; u++) {
            int e = tid + u * 256;
            int r = e >> 3, c = e & 7;
            *(int4*)&ldsY[r * LDP + c * 8] = gy[r * 16 + c];
        }
        __syncthreads();
#pragma unroll
        for (int kk = 0; kk < 2; ++kk) {
            short8 af[2], bf[4];
#pragma unroll
            for (int t = 0; t < 2; t++)
                af[t] = *(const short8*)&ldsX[(wj + t * 16 + l16) * LDP + kk * 32 + quad * 8];
#pragma unroll
            for (int t = 0; t < 4; t++)
                bf[t] = *(const short8*)&ldsY[(t * 16 + l16) * LDP + kk * 32 + quad * 8];
#pragma unroll
            for (int a = 0; a < 2; a++)
#pragma unroll
                for (int b = 0; b < 4; b++)
                    acc[a][b] = __builtin_amdgcn_mfma_f32_16x16x32_bf16(af[a], bf[b], acc[a][b], 0, 0, 0);
        }
    }
    // acc[a][b][r]: j_local = wj + a*16 + quad*4 + r, i_local = b*16 + l16

    if (PASS == 1) {
        const bool diag = ((bn >> 1) == bm);
        const int doff = (bn & 1) * 64;
        float sL[4] = {0.f, 0.f, 0.f, 0.f}, sE[4] = {0.f, 0.f, 0.f, 0.f};
#pragma unroll
        for (int b = 0; b < 4; b++) {
            const int il = b * 16 + l16;
            const float ynv = ldsYn[il];
#pragma unroll
            for (int a = 0; a < 2; a++) {
                const f32x4 xnv = *(const f32x4*)&ldsXn[wj + a * 16 + quad * 4];
#pragma unroll
                for (int r = 0; r < 4; r++) {
                    float s2 = fmaxf(fmaf(-2.f, acc[a][b][r], ynv + xnv[r]), 0.f);
                    float t = 1.f + s2;
                    float lg = fast_log2(t);
                    sL[b] += lg;
                    sE[b] += fast_rcp(t);
                    if (diag && (wj + a * 16 + quad * 4 + r) == doff + il)
                        pos[i0 + il] = -LN2 * lg;
                }
            }
        }
#pragma unroll
        for (int b = 0; b < 4; b++) {
            sL[b] += __shfl_xor(sL[b], 16); sL[b] += __shfl_xor(sL[b], 32);
            sE[b] += __shfl_xor(sE[b], 16); sE[b] += __shfl_xor(sE[b], 32);
            if (lane < 16) {
                atomicAdd(&rowA[b * 16 + l16], sL[b]);
                atomicAdd(&rowB[b * 16 + l16], sE[b]);
            }
        }
        __syncthreads();
        if (tid < TI) {
            atomicAdd(&TLr[i0 + tid], rowA[tid]);   // sum_j log2(1+s2) (incl. diag)
            atomicAdd(&R[i0 + tid], rowB[tid]);     // sum_j exp(L)     (incl. diag)
        }
    } else {
        float sw = 0.f, sp = 0.f, sq = 0.f;
#pragma unroll
        for (int b = 0; b < 4; b++) {
            const int il = b * 16 + l16;
            const float ynv = ldsYn[il];
            const float pe  = rowB[il];
#pragma unroll
            for (int a = 0; a < 2; a++) {
                const f32x4 xnv = *(const f32x4*)&ldsXn[wj + a * 16 + quad * 4];
#pragma unroll
                for (int r = 0; r < 4; r++) {
                    float s2 = fmaxf(fmaf(-2.f, acc[a][b][r], ynv + xnv[r]), 0.f);
                    float t = 1.f + s2;
                    float e = fast_rcp(t);
                    float u = pe + e;
                    sw += fast_log2(u);                      // way*log2e + 1
                    float v = pe * u;
                    sp = fmaf(v, fast_rcp(v + C2), sp);      // sigmoid(pos + way - LB)
                    sq = fmaf(u, fast_rcp(fmaf(C2, t, u)), sq); // sigmoid(way + L - LB)
                }
            }
        }
#pragma unroll
        for (int m = 1; m < 64; m <<= 1) { sw += __shfl_xor(sw, m); sp += __shfl_xor(sp, m); sq += __shfl_xor(sq, m); }
        if (lane == 0) { wred[wave][0] = sw; wred[wave][1] = sp; wred[wave][2] = sq; }
        __syncthreads();
        if (tid == 0) {
            float W = 0, P = 0, Q = 0;
            for (int w = 0; w < 4; w++) { W += wred[w][0]; P += wred[w][1]; Q += wred[w][2]; }
            atomicAdd(&sc[0], W); atomicAdd(&sc[1], P); atomicAdd(&sc[2], Q);
        }
    }
}

// ---------------- kernel 2: reduce rows -> LB, TP, diag corrections ----------------
__device__ __forceinline__ float block_sum(float v, float* sm)
{
#pragma unroll
    for (int m = 1; m < 64; m <<= 1) v += __shfl_xor(v, m);
    if ((threadIdx.x & 63) == 0) sm[threadIdx.x >> 6] = v;
    __syncthreads();
    float r = 0.f;
    if (threadIdx.x == 0) r = sm[0] + sm[1] + sm[2] + sm[3];
    __syncthreads();
    return r;  // valid on thread 0
}

__global__ __launch_bounds__(256) void k_mid(
    const float* __restrict__ pos, const float* __restrict__ R,
    const float* __restrict__ TLr, float* __restrict__ sc)
{
    __shared__ float sm[4];
    __shared__ float bc;
    const int tid = threadIdx.x;
    float sp = 0, sn = 0, tl = 0, ps = 0;
    for (int i = tid; i < N; i += 256) {
        float pv = pos[i], ep = fast_exp2(pv * LOG2E);
        sp += ep; sn += R[i] - ep;
        tl += -LN2 * TLr[i] - pv;
        ps += pv;
    }
    sp = block_sum(sp, sm);
    sn = block_sum(sn, sm);
    tl = block_sum(tl, sm);
    ps = block_sum(ps, sm);
    if (tid == 0) {
        const float logM = __logf((float)N * (float)(N - 1));
        float lb2 = __logf(sn) - logM;
        float lb1 = __logf(0.5f * ((float)(N - 1) * sp + sn)) - logM;
        float LB = lb1 + lb2;
        sc[3] = LB; sc[4] = ps; sc[5] = tl;
        bc = LB;
    }
    __syncthreads();
    const float LB = bc;
    float tp = 0, sgd = 0;
    for (int i = tid; i < N; i += 256) {
        float pv = pos[i], ep = fast_exp2(pv * LOG2E);
        float Roff = R[i] - ep;
        float pf = pv - LB + __logf(0.5f * ((float)(N - 1) * ep + Roff)) - __logf((float)(N - 1));
        tp += sig_nl2(-pf * LOG2E);
        sgd += sig_nl2(-(2.f * pv - LB) * LOG2E);
    }
    tp = block_sum(tp, sm);
    sgd = block_sum(sgd, sm);
    if (tid == 0) { sc[6] = tp / (float)N; sc[7] = sgd; }
}

// ---------------- finalize 9 outputs ----------------
__global__ void k_fin(const float* __restrict__ sc, float* __restrict__ out)
{
    if (threadIdx.x == 0 && blockIdx.x == 0) {
        const float M = (float)N * (float)(N - 1);
        float W   = LN2 * (sc[0] - (float)N * (float)N) - sc[4];  // off-diag sum of way
        float SGP = sc[1] - sc[7];
        float SGN = sc[2] - sc[7];
        float LB = sc[3], Sp = sc[4], TL = sc[5], TP = sc[6];
        float o0 = Sp / (float)N + W / M - LB;
        float o1 = W / M + TL / M - LB;
        float o2 = SGP / M, o3 = SGN / M;
        float FP = o3;
        out[0] = o0;
        out[1] = o1;
        out[2] = o2;
        out[3] = o3;
        out[4] = (TP + (1.f - FP)) * 0.5f;
        out[5] = TP;
        out[6] = TP / (TP + FP);
        out[7] = LB;
        out[8] = -o0 + 2.0f;
    }
}

extern "C" void kernel_launch(void* const* d_in, const int* in_sizes, int n_in,
                              void* d_out, int out_size, void* d_ws, size_t ws_size,
                              hipStream_t stream)
{
    const float* X = (const float*)d_in[0];  // z_x (j / columns of logits)
    const float* Y = (const float*)d_in[1];  // z_y (i / rows of logits)
    float* out = (float*)d_out;

    char* ws = (char*)d_ws;
    __hip_bfloat16* Yb = (__hip_bfloat16*)(ws);
    __hip_bfloat16* Xb = (__hip_bfloat16*)(ws + (1 << 20));
    float* yn  = (float*)(ws + (2 << 20));
    float* xn  = yn + N;
    float* pos = xn + N;
    float* R   = pos + N;
    float* TLr = R + N;
    float* sc  = TLr + N;

    k_prep<<<N, 128, 0, stream>>>(X, Y, Xb, Yb, xn, yn, R, TLr, sc);
    k_mat<1><<<dim3(N / TI, N / TJ), 256, 0, stream>>>(Yb, Xb, yn, xn, pos, R, TLr, sc);
    k_mid<<<1, 256, 0, stream>>>(pos, R, TLr, sc);
    k_mat<2><<<dim3(N / TI, N / TJ), 256, 0, stream>>>(Yb, Xb, yn, xn, pos, R, TLr, sc);
    k_fin<<<1, 64, 0, stream>>>(sc, out);
}

// Round 4
// 105.257 us; speedup vs baseline: 1.6450x; 1.6450x over previous
//
#include <hip/hip_runtime.h>
#include <hip/hip_bf16.h>

#define N 4096
#define D 128
#define TILE 128
#define LDP 72   // 64 K-chunk + 8 bf16 pad

typedef __attribute__((ext_vector_type(8))) short short8;
typedef __attribute__((ext_vector_type(4))) float f32x4;
typedef __attribute__((ext_vector_type(4))) _Float16 h16x4;

#define LOG2E 1.44269504088896340736f
#define LN2   0.69314718055994530942f

// E-file: 2^22 groups of 4 fp16 (8B) = 32 MB
#define EGROUPS (1u << 22)

#if __has_builtin(__builtin_amdgcn_rcpf)
__device__ __forceinline__ float fast_rcp(float x) { return __builtin_amdgcn_rcpf(x); }
#else
__device__ __forceinline__ float fast_rcp(float x) { return 1.f / x; }
#endif
#if __has_builtin(__builtin_amdgcn_logf)
__device__ __forceinline__ float fast_log2(float x) { return __builtin_amdgcn_logf(x); }
#else
__device__ __forceinline__ float fast_log2(float x) { return __log2f(x); }
#endif
#if __has_builtin(__builtin_amdgcn_exp2f)
__device__ __forceinline__ float fast_exp2(float x) { return __builtin_amdgcn_exp2f(x); }
#else
__device__ __forceinline__ float fast_exp2(float x) { return exp2f(x); }
#endif

__device__ __forceinline__ float sig_nl2(float nl2) {  // sigmoid(x), nl2 = -x*log2e
    return fast_rcp(1.f + fast_exp2(nl2));
}

// ---------------- kernel 0: cast to bf16, exact fp32 row norms, zero accumulators ----------------
__global__ __launch_bounds__(128) void k_prep(
    const float* __restrict__ X, const float* __restrict__ Y,
    __hip_bfloat16* __restrict__ Xb, __hip_bfloat16* __restrict__ Yb,
    float* __restrict__ xn, float* __restrict__ yn,
    float* __restrict__ R, float* __restrict__ TLr, float* __restrict__ sc)
{
    const int row = blockIdx.x, t = threadIdx.x;
    const float vx = X[row * D + t], vy = Y[row * D + t];
    Xb[row * D + t] = __float2bfloat16(vx);
    Yb[row * D + t] = __float2bfloat16(vy);
    float px = vx * vx, py = vy * vy;
#pragma unroll
    for (int m = 1; m < 64; m <<= 1) { px += __shfl_xor(px, m); py += __shfl_xor(py, m); }
    __shared__ float s[2][2];
    if ((t & 63) == 0) { s[t >> 6][0] = px; s[t >> 6][1] = py; }
    __syncthreads();
    if (t == 0) { xn[row] = s[0][0] + s[1][0]; yn[row] = s[0][1] + s[1][1]; }
    const int g = row * D + t;
    if (g < N) { R[g] = 0.f; TLr[g] = 0.f; }
    if (g < 16) sc[g] = 0.f;
}

// ---------------- matmul + fused epilogue (R2-proven 128x128 config) ----------------
// i0 = bm*128 (Y rows / logit rows), j0 = bn*128 (X rows / logit cols)
// PASS=1: per-i sums of log2(1+s2) and 1/(1+s2); optional fp16 E store (swizzled layout)
// PASS=2 (fallback only): global sums (way-log2, 2 sigmoids)
template <int PASS, bool STORE>
__global__ __launch_bounds__(256) void k_mat(
    const __hip_bfloat16* __restrict__ Yb, const __hip_bfloat16* __restrict__ Xb,
    const float* __restrict__ yn, const float* __restrict__ xn,
    float* __restrict__ pos, float* __restrict__ R, float* __restrict__ TLr,
    float* __restrict__ sc, h16x4* __restrict__ Eg)
{
    __shared__ short ldsY[TILE * LDP];   // i side (B operand)
    __shared__ short ldsX[TILE * LDP];   // j side (A operand)
    __shared__ __align__(16) float ldsYn[TILE];
    __shared__ __align__(16) float ldsXn[TILE];
    __shared__ float rowA[TILE], rowB[TILE];
    __shared__ float wred[4][3];

    const int tid = threadIdx.x;
    const int bm = blockIdx.y, bn = blockIdx.x;
    const int row0 = bm * TILE, col0 = bn * TILE;   // row0 -> i (Y), col0 -> j (X)
    const int lane = tid & 63, wave = tid >> 6;
    const int wj = (wave >> 1) * 64;   // j offset within tile (C rows)
    const int wi = (wave & 1) * 64;    // i offset within tile (C cols)
    const int l16 = lane & 15, quad = lane >> 4;

    if (tid < TILE) {
        ldsYn[tid] = yn[row0 + tid];
        ldsXn[tid] = xn[col0 + tid];
        if (PASS == 1) { rowA[tid] = 0.f; rowB[tid] = 0.f; }
        else { float p = pos[row0 + tid]; rowA[tid] = p; rowB[tid] = fast_exp2(p * LOG2E); }
    }
    const float LB = (PASS == 2) ? sc[3] : 0.f;
    const float C2 = (PASS == 2) ? 2.f * fast_exp2(LB * LOG2E) : 0.f;

    f32x4 acc[4][4];
#pragma unroll
    for (int a = 0; a < 4; a++)
#pragma unroll
        for (int b = 0; b < 4; b++) acc[a][b] = f32x4{0.f, 0.f, 0.f, 0.f};

#pragma unroll
    for (int ks = 0; ks < 2; ++ks) {
        if (ks) __syncthreads();
        const int4* gy = (const int4*)(Yb + (size_t)row0 * D + ks * 64);
        const int4* gx = (const int4*)(Xb + (size_t)col0 * D + ks * 64);
#pragma unroll
        for (int u = 0; u < 4; u++) {
            int e = tid + u * 256;
            int r = e >> 3, c = e & 7;
            *(int4*)&ldsY[r * LDP + c * 8] = gy[r * 16 + c];
            *(int4*)&ldsX[r * LDP + c * 8] = gx[r * 16 + c];
        }
        __syncthreads();
#pragma unroll
        for (int kk = 0; kk < 2; ++kk) {
            short8 af[4], bf[4];
#pragma unroll
            for (int t = 0; t < 4; t++) {
                af[t] = *(const short8*)&ldsX[(wj + t * 16 + l16) * LDP + kk * 32 + quad * 8];
                bf[t] = *(const short8*)&ldsY[(wi + t * 16 + l16) * LDP + kk * 32 + quad * 8];
            }
#pragma unroll
            for (int a = 0; a < 4; a++)
#pragma unroll
                for (int b = 0; b < 4; b++)
                    acc[a][b] = __builtin_amdgcn_mfma_f32_16x16x32_bf16(af[a], bf[b], acc[a][b], 0, 0, 0);
        }
    }
    // acc[a][b][r]: j = col0 + wj + a*16 + quad*4 + r, i = row0 + wi + b*16 + l16

    if (PASS == 1) {
        // E-file group index: (((bn*32 + bm)*4 + wave)*16 + a*4+b)*64 + lane
        const unsigned wgbase = (((unsigned)bn * 32u + (unsigned)bm) * 4u + (unsigned)wave) * 1024u + (unsigned)lane;
        float sL[4] = {0.f, 0.f, 0.f, 0.f}, sE[4] = {0.f, 0.f, 0.f, 0.f};
        const bool diag = (row0 == col0);
#pragma unroll
        for (int a = 0; a < 4; a++) {
            const int jl = wj + a * 16 + quad * 4;
            const f32x4 xnv = *(const f32x4*)&ldsXn[jl];
#pragma unroll
            for (int b = 0; b < 4; b++) {
                const int il = wi + b * 16 + l16;
                const float ynv = ldsYn[il];
                h16x4 hv;
#pragma unroll
                for (int r = 0; r < 4; r++) {
                    float s2 = fmaxf(fmaf(-2.f, acc[a][b][r], ynv + xnv[r]), 0.f);
                    float t = 1.f + s2;
                    float lg = fast_log2(t);
                    float e = fast_rcp(t);
                    sL[b] += lg;
                    sE[b] += e;
                    hv[r] = (_Float16)e;
                    if (diag && il == jl + r) pos[row0 + il] = -LN2 * lg;
                }
                if (STORE) Eg[wgbase + (unsigned)(a * 4 + b) * 64u] = hv;
            }
        }
#pragma unroll
        for (int b = 0; b < 4; b++) {
            sL[b] += __shfl_xor(sL[b], 16); sL[b] += __shfl_xor(sL[b], 32);
            sE[b] += __shfl_xor(sE[b], 16); sE[b] += __shfl_xor(sE[b], 32);
            if (lane < 16) {
                atomicAdd(&rowA[wi + b * 16 + l16], sL[b]);
                atomicAdd(&rowB[wi + b * 16 + l16], sE[b]);
            }
        }
        __syncthreads();
        if (tid < TILE) {
            atomicAdd(&TLr[row0 + tid], rowA[tid]);   // sum_j log2(1+s2)  (incl. diag)
            atomicAdd(&R[row0 + tid], rowB[tid]);     // sum_j exp(L)      (incl. diag)
        }
    } else {
        float sw = 0.f, sp = 0.f, sq = 0.f;
#pragma unroll
        for (int b = 0; b < 4; b++) {
            const int il = wi + b * 16 + l16;
            const float ynv = ldsYn[il];
            const float pe  = rowB[il];
#pragma unroll
            for (int a = 0; a < 4; a++) {
                const f32x4 xnv = *(const f32x4*)&ldsXn[wj + a * 16 + quad * 4];
#pragma unroll
                for (int r = 0; r < 4; r++) {
                    float s2 = fmaxf(fmaf(-2.f, acc[a][b][r], ynv + xnv[r]), 0.f);
                    float t = 1.f + s2;
                    float e = fast_rcp(t);
                    float u = pe + e;
                    sw += fast_log2(u);
                    float v = pe * u;
                    sp = fmaf(v, fast_rcp(v + C2), sp);
                    float ue = e * u;
                    sq = fmaf(ue, fast_rcp(ue + C2), sq);
                }
            }
        }
#pragma unroll
        for (int m = 1; m < 64; m <<= 1) { sw += __shfl_xor(sw, m); sp += __shfl_xor(sp, m); sq += __shfl_xor(sq, m); }
        if (lane == 0) { wred[wave][0] = sw; wred[wave][1] = sp; wred[wave][2] = sq; }
        __syncthreads();
        if (tid == 0) {
            float W = 0, P = 0, Q = 0;
            for (int w = 0; w < 4; w++) { W += wred[w][0]; P += wred[w][1]; Q += wred[w][2]; }
            atomicAdd(&sc[0], W); atomicAdd(&sc[1], P); atomicAdd(&sc[2], Q);
        }
    }
}

// ---------------- kernel 2: reduce rows -> LB, TP, diag corrections, pe table ----------------
__device__ __forceinline__ float block_sum(float v, float* sm)
{
#pragma unroll
    for (int m = 1; m < 64; m <<= 1) v += __shfl_xor(v, m);
    if ((threadIdx.x & 63) == 0) sm[threadIdx.x >> 6] = v;
    __syncthreads();
    float r = 0.f;
    if (threadIdx.x == 0) r = sm[0] + sm[1] + sm[2] + sm[3];
    __syncthreads();
    return r;  // valid on thread 0
}

__global__ __launch_bounds__(256) void k_mid(
    const float* __restrict__ pos, const float* __restrict__ R,
    const float* __restrict__ TLr, float* __restrict__ sc,
    float* __restrict__ pe_tab)
{
    __shared__ float sm[4];
    __shared__ float bc;
    const int tid = threadIdx.x;
    float sp = 0, sn = 0, tl = 0, ps = 0;
    for (int i = tid; i < N; i += 256) {
        float pv = pos[i], ep = fast_exp2(pv * LOG2E);
        pe_tab[i] = ep;
        sp += ep; sn += R[i] - ep;
        tl += -LN2 * TLr[i] - pv;
        ps += pv;
    }
    sp = block_sum(sp, sm);
    sn = block_sum(sn, sm);
    tl = block_sum(tl, sm);
    ps = block_sum(ps, sm);
    if (tid == 0) {
        const float logM = __logf((float)N * (float)(N - 1));
        float lb2 = __logf(sn) - logM;
        float lb1 = __logf(0.5f * ((float)(N - 1) * sp + sn)) - logM;
        float LB = lb1 + lb2;
        sc[3] = LB; sc[4] = ps; sc[5] = tl;
        bc = LB;
    }
    __syncthreads();
    const float LB = bc;
    float tp = 0, sgd = 0;
    for (int i = tid; i < N; i += 256) {
        float pv = pos[i], ep = fast_exp2(pv * LOG2E);
        float Roff = R[i] - ep;
        float pf = pv - LB + __logf(0.5f * ((float)(N - 1) * ep + Roff)) - __logf((float)(N - 1));
        tp += sig_nl2(-pf * LOG2E);
        sgd += sig_nl2(-(2.f * pv - LB) * LOG2E);
    }
    tp = block_sum(tp, sm);
    sgd = block_sum(sgd, sm);
    if (tid == 0) { sc[6] = tp / (float)N; sc[7] = sgd; }
}

// ---------------- streaming pass 2: read E-file, accumulate 3 global sums ----------------
// group g: lane=g&63, ab=(g>>6)&15 (a=ab>>2,b=ab&3), wave=(g>>10)&3, bm=(g>>12)&31, bn=g>>17
// i = bm*128 + (wave&1)*64 + b*16 + (lane&15)
__global__ __launch_bounds__(256) void k_sig(
    const h16x4* __restrict__ Eg, const float* __restrict__ pe_tab,
    const float* __restrict__ sc, float* __restrict__ wpart)
{
    __shared__ float wred[4][3];
    const int tid = threadIdx.x, bid = blockIdx.x;
    const float C2 = 2.f * fast_exp2(sc[3] * LOG2E);
    float sw = 0.f, sp = 0.f, sq = 0.f;
    unsigned g = (unsigned)bid * 256u + (unsigned)tid;
#pragma unroll 4
    for (int it = 0; it < 16; ++it, g += 1024u * 256u) {
        h16x4 hv = Eg[g];
        const int i = (int)(((g >> 12) & 31u) * 128u + ((g >> 10) & 1u) * 64u
                            + ((g >> 6) & 3u) * 16u + (g & 15u));
        const float pe = pe_tab[i];
#pragma unroll
        for (int r = 0; r < 4; r++) {
            float e = (float)hv[r];
            float u = pe + e;
            sw += fast_log2(u);              // way*log2e + 1
            float v = pe * u;
            sp = fmaf(v, fast_rcp(v + C2), sp);   // sigmoid(pos + way - LB)
            float ue = e * u;
            sq = fmaf(ue, fast_rcp(ue + C2), sq); // sigmoid(way + L - LB)
        }
    }
    const int lane = tid & 63, wave = tid >> 6;
#pragma unroll
    for (int m = 1; m < 64; m <<= 1) { sw += __shfl_xor(sw, m); sp += __shfl_xor(sp, m); sq += __shfl_xor(sq, m); }
    if (lane == 0) { wred[wave][0] = sw; wred[wave][1] = sp; wred[wave][2] = sq; }
    __syncthreads();
    if (tid == 0) {
        float W = 0, P = 0, Q = 0;
        for (int w = 0; w < 4; w++) { W += wred[w][0]; P += wred[w][1]; Q += wred[w][2]; }
        wpart[bid * 3 + 0] = W; wpart[bid * 3 + 1] = P; wpart[bid * 3 + 2] = Q;
    }
}

// ---------------- finalize 9 outputs (reduces k_sig partials if nparts>0) ----------------
__global__ __launch_bounds__(256) void k_fin(
    const float* __restrict__ sc, const float* __restrict__ wpart, int nparts,
    float* __restrict__ out)
{
    __shared__ float sm[4];
    const int tid = threadIdx.x;
    float W, P, Q;
    if (nparts > 0) {
        float w = 0, p = 0, q = 0;
        for (int r = tid; r < nparts; r += 256) {
            w += wpart[r * 3 + 0]; p += wpart[r * 3 + 1]; q += wpart[r * 3 + 2];
        }
        W = block_sum(w, sm); P = block_sum(p, sm); Q = block_sum(q, sm);
    } else {
        W = sc[0]; P = sc[1]; Q = sc[2];
    }
    if (tid == 0) {
        const float M = (float)N * (float)(N - 1);
        float Wo  = LN2 * (W - (float)N * (float)N) - sc[4];  // off-diag sum of way
        float SGP = P - sc[7];
        float SGN = Q - sc[7];
        float LB = sc[3], Sp = sc[4], TL = sc[5], TP = sc[6];
        float o0 = Sp / (float)N + Wo / M - LB;
        float o1 = Wo / M + TL / M - LB;
        float o2 = SGP / M, o3 = SGN / M;
        float FP = o3;
        out[0] = o0;
        out[1] = o1;
        out[2] = o2;
        out[3] = o3;
        out[4] = (TP + (1.f - FP)) * 0.5f;
        out[5] = TP;
        out[6] = TP / (TP + FP);
        out[7] = LB;
        out[8] = -o0 + 2.0f;
    }
}

extern "C" void kernel_launch(void* const* d_in, const int* in_sizes, int n_in,
                              void* d_out, int out_size, void* d_ws, size_t ws_size,
                              hipStream_t stream)
{
    const float* X = (const float*)d_in[0];  // z_x (j / columns of logits)
    const float* Y = (const float*)d_in[1];  // z_y (i / rows of logits)
    float* out = (float*)d_out;

    char* ws = (char*)d_ws;
    __hip_bfloat16* Yb = (__hip_bfloat16*)(ws);
    __hip_bfloat16* Xb = (__hip_bfloat16*)(ws + (1 << 20));
    float* yn   = (float*)(ws + (2 << 20));
    float* xn   = yn + N;
    float* pos  = xn + N;
    float* R    = pos + N;
    float* TLr  = R + N;
    float* pe   = TLr + N;
    float* sc   = pe + N;          // 16 scalars
    float* wpart = sc + 16;        // 1024*3 partials
    h16x4* Eg   = (h16x4*)(ws + (4 << 20));   // 32 MB E-file

    const bool big = ws_size >= ((size_t)37 << 20);

    k_prep<<<N, 128, 0, stream>>>(X, Y, Xb, Yb, xn, yn, R, TLr, sc);
    if (big) {
        k_mat<1, true><<<dim3(N / TILE, N / TILE), 256, 0, stream>>>(Yb, Xb, yn, xn, pos, R, TLr, sc, Eg);
        k_mid<<<1, 256, 0, stream>>>(pos, R, TLr, sc, pe);
        k_sig<<<1024, 256, 0, stream>>>(Eg, pe, sc, wpart);
        k_fin<<<1, 256, 0, stream>>>(sc, wpart, 1024, out);
    } else {
        k_mat<1, false><<<dim3(N / TILE, N / TILE), 256, 0, stream>>>(Yb, Xb, yn, xn, pos, R, TLr, sc, Eg);
        k_mid<<<1, 256, 0, stream>>>(pos, R, TLr, sc, pe);
        k_mat<2, false><<<dim3(N / TILE, N / TILE), 256, 0, stream>>>(Yb, Xb, yn, xn, pos, R, TLr, sc, Eg);
        k_fin<<<1, 256, 0, stream>>>(sc, wpart, 0, out);
    }
}